// Round 1
// 132.201 us; speedup vs baseline: 1.0198x; 1.0198x over previous
//
#include <hip/hip_runtime.h>

// Problem constants
#define NB 8
#define NSEQ 1024
#define NC 768
#define NH 12
#define ND 64
#define NM 8192                     // NB*NSEQ rows

typedef _Float16 v8h __attribute__((ext_vector_type(8)));
typedef float v4f __attribute__((ext_vector_type(4)));

__device__ __forceinline__ float q8f(float x){ return rintf(x*128.f)*0.0078125f; }
__device__ __forceinline__ float q4f(float x){ return rintf(x*8.f)*0.125f; }

// swizzled half-index: row r, 8-half granule g (row stride 64 halves)
__device__ __forceinline__ int swz(int r, int g){ return (r<<6) + (((g ^ (r & 7)) & 7)<<3); }

// async 16B global->LDS (lds dest = uniform base + lane*16)
__device__ __forceinline__ void async_cp16(const _Float16* g, _Float16* l) {
  __builtin_amdgcn_global_load_lds(
      (const __attribute__((address_space(1))) unsigned int*)g,
      (__attribute__((address_space(3))) unsigned int*)l, 16, 0, 0);
}

// ---------------------------------------------------------------------------
// Kernel 0: (a) fp32 -> q8 fp16 tiled/swizzled for x and w_qk (first 1536
// rows of w_qkv); (b) fill out with bias (hit fix-ups atomicAdd later).
// ---------------------------------------------------------------------------
__global__ __launch_bounds__(256) void k_pre(const float* __restrict__ x,
                                             const float* __restrict__ wq,
                                             const float* __restrict__ bias,
                                             _Float16* __restrict__ xt,
                                             _Float16* __restrict__ wqt,
                                             float* __restrict__ out) {
  int b = blockIdx.x;
  if (b < 3648) {
    const float* src; _Float16* dst; int gid;
    if (b < 3072) { src = x;  dst = xt;  gid = b*256 + threadIdx.x; }
    else          { src = wq; dst = wqt; gid = (b-3072)*256 + threadIdx.x; }
    int tile = gid / 12288;               // 12 chunks * 1024 granules
    int rem  = gid - tile*12288;
    int chunk = rem >> 10, idx = rem & 1023;
    int r = idx >> 3, g = idx & 7;
    const float* s = src + (size_t)(tile*128 + r)*768 + chunk*64 + g*8;
    float4 v0 = *(const float4*)s, v1 = *(const float4*)(s + 4);
    v8h o;
    o[0]=(_Float16)q8f(v0.x); o[1]=(_Float16)q8f(v0.y); o[2]=(_Float16)q8f(v0.z); o[3]=(_Float16)q8f(v0.w);
    o[4]=(_Float16)q8f(v1.x); o[5]=(_Float16)q8f(v1.y); o[6]=(_Float16)q8f(v1.z); o[7]=(_Float16)q8f(v1.w);
    *(v8h*)&dst[((size_t)tile*12 + chunk)*8192 + swz(r, g)] = o;
  } else {
    int gid = (b - 3648)*256 + threadIdx.x;   // over 1572864 float4s
    int c4 = gid % 192;
    ((float4*)out)[gid] = ((const float4*)bias)[c4];
  }
}

// MFMA on one staged 128x128(A) x 128x64-chunk: 16x16x32 f16
__device__ __forceinline__ void mfma_tile(const _Float16* Ah, const _Float16* Bh,
                                          int WR0, int l15, int quad, v4f acc[2][8]) {
#pragma unroll
  for (int ks = 0; ks < 2; ks++) {
    v8h a0 = *(const v8h*)&Ah[swz(WR0 + l15,      ks*4 + quad)];
    v8h a1 = *(const v8h*)&Ah[swz(WR0 + 16 + l15, ks*4 + quad)];
#pragma unroll
    for (int nt = 0; nt < 8; nt++) {
      v8h b = *(const v8h*)&Bh[swz(nt*16 + l15, ks*4 + quad)];
      acc[0][nt] = __builtin_amdgcn_mfma_f32_16x16x32_f16(a0, b, acc[0][nt], 0, 0, 0);
      acc[1][nt] = __builtin_amdgcn_mfma_f32_16x16x32_f16(a1, b, acc[1][nt], 0, 0, 0);
    }
  }
}

// ---------------------------------------------------------------------------
// Kernel 1: Q/K GEMM (M=8192, N=1536, K=768). 128x128 tile (measured best:
// 64KB LDS -> 2 blocks/CU, R7/R8/R10 profile). Outputs ONLY the MSB tensors:
// Q-blocks: Qm = q4(q8)*0.125 [m][768]; K-blocks: KmT [bh][16][4096 swizzled].
// ---------------------------------------------------------------------------
__global__ __launch_bounds__(256) void k_qk(const _Float16* __restrict__ xt,
                                            const _Float16* __restrict__ wqt,
                                            _Float16* __restrict__ Qm,
                                            _Float16* __restrict__ KmT) {
  __shared__ _Float16 S[2][16384];        // per buf: A 8192 | B 8192
  const int tid  = threadIdx.x;
  const int lane = tid & 63;
  const int quad = lane >> 4;
  const int l15  = lane & 15;
  const int wid  = tid >> 6;
  const int WR0  = wid * 32;
  const int m0 = blockIdx.x * 128, n0 = blockIdx.y * 128;
  const _Float16* Asrc = xt  + (size_t)blockIdx.x * 12 * 8192;
  const _Float16* Bsrc = wqt + (size_t)blockIdx.y * 12 * 8192;

  auto stage = [&](int kc, int bi) {
    const _Float16* a = Asrc + kc*8192;
    const _Float16* bsc = Bsrc + kc*8192;
#pragma unroll
    for (int s = 0; s < 8; s++) {
      int seg = wid*8 + s;
      const _Float16* g = (seg < 16 ? a + seg*512 : bsc + (seg-16)*512) + lane*8;
      async_cp16(g, &S[bi][seg*512]);
    }
  };

  v4f acc[2][8] = {};
  stage(0, 0);
#pragma unroll 1
  for (int kc = 0; kc < 12; kc++) {
    __syncthreads();
    if (kc + 1 < 12) stage(kc + 1, (kc + 1) & 1);
    mfma_tile(&S[kc & 1][0], &S[kc & 1][8192], WR0, l15, quad, acc);
  }

  const int which = (n0 >= 768);          // 0: Q block, 1: K block
  _Float16* P = &S[0][0];                 // bounce area 128x132
  __syncthreads();
#pragma unroll
  for (int mt = 0; mt < 2; mt++)
#pragma unroll
    for (int nt = 0; nt < 8; nt++)
#pragma unroll
      for (int rr = 0; rr < 4; rr++) {
        float v = q8f(acc[mt][nt][rr]);
        float qm = (which == 0) ? q4f(v) * 0.125f : q4f(v);
        P[(WR0 + mt*16 + quad*4 + rr)*132 + nt*16 + l15] = (_Float16)qm;
      }
  __syncthreads();
  int c0 = n0 - which*768;
#pragma unroll
  for (int t = 0; t < 8; t++) {
    int idx = tid + t*256;
    int r = idx >> 4, cg = idx & 15;
    v8h val = *(const v8h*)&P[r*132 + cg*8];
    if (which == 0) {
      *(v8h*)&Qm[(size_t)(m0 + r)*768 + c0 + cg*8] = val;
    } else {
      int m = m0 + r, col = c0 + cg*8;
      int bI = m >> 10, n = m & 1023;
      int h = col >> 6, g = (col >> 3) & 7;
      size_t dst = ((size_t)(bI*NH + h)*16 + (n >> 6))*4096 + swz(n & 63, g);
      *(v8h*)&KmT[dst] = val;
    }
  }
}

// ---------------------------------------------------------------------------
// Kernel 2: MSB screen + slow path + inline hit fix-up. 128-row Q tiles.
// TWO K-chunks staged per barrier (8 barriers, 32 MFMA each).
// Grid is (96, 8): bh on blockIdx.x so the 8 q-tile blocks sharing one bh's
// 128KB KmT panel get the same linear-id residue mod 8 -> same XCD -> K
// panel is L2-resident instead of 8x HBM re-fetch (per-XCD working set:
// 12 bh x 128KB K + ~1.5MB Qm slices ~= 3MB < 4MB XCD L2).
// Screen: per-chunk group max; running (max, 2nd-group-max). Underestimating
// m2 only ADDS slow-path candidates (never false negatives). gap<=4.5 proves
// pm <= 0.989 < 0.99.
// ---------------------------------------------------------------------------
__global__ __launch_bounds__(256) void k_attn(const _Float16* __restrict__ QmG,
                                              const _Float16* __restrict__ KmT,
                                              const float* __restrict__ x,
                                              const float* __restrict__ wqkv,
                                              const float* __restrict__ wproj,
                                              float* __restrict__ out) {
  __shared__ _Float16 S2[2][8192];        // two chunks per buffer
  __shared__ float rowm[128];
  __shared__ int   cand[128];
  __shared__ int   hrowA[128];
  __shared__ int   hcolA[128];
  __shared__ float qf[64], kf[64], vf[64];
  __shared__ float od[64];
  __shared__ float pps;
  __shared__ int   cnt, hcnt;

  const int tid  = threadIdx.x;
  const int lane = tid & 63;
  const int quad = lane >> 4;
  const int l15  = lane & 15;
  const int wid  = tid >> 6;
  const int R0   = wid * 16;
  const int bh = blockIdx.x;              // bh fastest -> same-XCD K reuse
  const int q0 = blockIdx.y * 128;
  const int bb = bh / NH, hb = bh % NH;
  const size_t mrow = (size_t)bb * NSEQ;
  const int hoff = hb * 64;
  const _Float16* KmB = KmT + (size_t)bh * 16 * 4096;

  if (tid == 0) { cnt = 0; hcnt = 0; }

  auto stageK2 = [&](int kp, int bi) {     // stages chunks 2kp, 2kp+1
#pragma unroll
    for (int s = 0; s < 4; s++) {
      int seg = wid*4 + s;                 // 16 segs x 512 halves
      async_cp16(KmB + kp*8192 + seg*512 + lane*8, &S2[bi][seg*512]);
    }
  };

  // A-fragments for both 64-row bands
  v8h aM[2][2];
#pragma unroll
  for (int b2 = 0; b2 < 2; b2++)
#pragma unroll
    for (int ks = 0; ks < 2; ks++)
      aM[b2][ks] = *(const v8h*)&QmG[(mrow + q0 + b2*64 + R0 + l15)*768 + hoff + ks*32 + quad*8];

  float lm[2][4], lm2[2][4];
#pragma unroll
  for (int b2 = 0; b2 < 2; b2++)
#pragma unroll
    for (int r = 0; r < 4; r++) { lm[b2][r] = -1e30f; lm2[b2][r] = -1e30f; }

  stageK2(0, 0);
#pragma unroll 1
  for (int kp = 0; kp < 8; kp++) {
    __syncthreads();
    if (kp + 1 < 8) stageK2(kp + 1, (kp + 1) & 1);
#pragma unroll
    for (int half = 0; half < 2; half++) {
      const _Float16* Kms = &S2[kp & 1][half*4096];
      v4f a0[4] = {}, a1[4] = {};
      __builtin_amdgcn_s_setprio(1);       // T5: favor MFMA-issuing wave
#pragma unroll
      for (int nt = 0; nt < 4; nt++)
#pragma unroll
        for (int ks = 0; ks < 2; ks++) {
          v8h b = *(const v8h*)&Kms[swz(l15 + 16*nt, ks*4 + quad)];
          a0[nt] = __builtin_amdgcn_mfma_f32_16x16x32_f16(aM[0][ks], b, a0[nt], 0, 0, 0);
          a1[nt] = __builtin_amdgcn_mfma_f32_16x16x32_f16(aM[1][ks], b, a1[nt], 0, 0, 0);
        }
      __builtin_amdgcn_s_setprio(0);
#pragma unroll
      for (int r = 0; r < 4; r++) {
        float c0 = fmaxf(fmaxf(a0[0][r], a0[1][r]), fmaxf(a0[2][r], a0[3][r]));
        lm2[0][r] = fmaxf(lm2[0][r], fminf(lm[0][r], c0));
        lm[0][r]  = fmaxf(lm[0][r], c0);
        float c1 = fmaxf(fmaxf(a1[0][r], a1[1][r]), fmaxf(a1[2][r], a1[3][r]));
        lm2[1][r] = fmaxf(lm2[1][r], fminf(lm[1][r], c1));
        lm[1][r]  = fmaxf(lm[1][r], c1);
      }
    }
  }
  // butterfly top-2 merge across the 16 lanes of each quad-row
#pragma unroll
  for (int b2 = 0; b2 < 2; b2++)
#pragma unroll
    for (int r = 0; r < 4; r++) {
      float m = lm[b2][r], m2 = lm2[b2][r];
#pragma unroll
      for (int o = 1; o < 16; o <<= 1) {
        float om  = __shfl_xor(m, o);
        float om2 = __shfl_xor(m2, o);
        m2 = fmaxf(fmaxf(m2, om2), fminf(m, om));
        m  = fmaxf(m, om);
      }
      if (l15 == 0 && (m - m2) > 4.5f) {
        int row = b2*64 + R0 + quad*4 + r;
        rowm[row] = m;
        int ix = atomicAdd(&cnt, 1);
        cand[ix] = row;
      }
    }
  __syncthreads();

  // slow path: exact denominator + argmax for candidates (one wave each)
  int nc = cnt;
  for (int ci = wid; ci < nc; ci += 4) {
    int row = cand[ci];
    float m = rowm[row];
    const _Float16* qrow = &QmG[(mrow + q0 + row)*768 + hoff];
    float l = 0.f, bmax = -1e30f;
    int bcol = 0;
    for (int t = 0; t < 16; t++) {
      float s = 0.f;
#pragma unroll
      for (int g = 0; g < 8; g++) {
        v8h qa = *(const v8h*)&qrow[g*8];
        v8h kb = *(const v8h*)&KmB[t*4096 + swz(lane, g)];
#pragma unroll
        for (int j = 0; j < 8; j++) s += (float)qa[j] * (float)kb[j];
      }
      l += expf(s - m);
      if (s > bmax) { bmax = s; bcol = t*64 + lane; }
    }
#pragma unroll
    for (int o = 1; o < 64; o <<= 1) {
      l += __shfl_xor(l, o);
      float ov = __shfl_xor(bmax, o);
      int   oc = __shfl_xor(bcol, o);
      if (ov > bmax || (ov == bmax && oc < bcol)) { bmax = ov; bcol = oc; }
    }
    if (lane == 0 && (1.0f / l) > 0.99f) {
      int ix = atomicAdd(&hcnt, 1);
      hrowA[ix] = row; hcolA[ix] = bcol;
    }
  }
  __syncthreads();

  // hit fix-up (rare; usually hcnt == 0)
  int nh = hcnt;
  for (int hi = 0; hi < nh; hi++) {
    int row = hrowA[hi], cst = hcolA[hi];
    if (tid < 192) {                     // recompute q/k/v head-slices exactly
      int d = tid & 63, part = tid >> 6; // 0:q 1:k 2:v
      int wrow = part*768 + hoff + d;
      int xrow = (part == 0) ? (int)(mrow + q0 + row) : (int)(mrow + cst);
      const float* xr = &x[(size_t)xrow*768];
      const float* wr = &wqkv[(size_t)wrow*768];
      float s = 0.f;
      for (int k = 0; k < 768; k++) s += q8f(xr[k]) * q8f(wr[k]);
      float v = q8f(s);
      if (part == 0) qf[d] = v; else if (part == 1) kf[d] = v; else vf[d] = v;
    }
    __syncthreads();
    if (tid == 0) {
      float s = 0.f;
      for (int d = 0; d < 64; d++) s += qf[d]*kf[d];
      float sf = s * 0.125f;
      float m2 = fmaxf(sf, 0.f);
      float l2 = expf(sf - m2) + 1023.f*expf(-m2);
      pps = rintf(expf(sf - m2)/l2*128.f)*0.0078125f;
    }
    __syncthreads();
    float p = pps;                        // block-uniform
    if (p != 0.f) {
      if (tid < 64) od[tid] = q8f(p * vf[tid]);
      __syncthreads();
      for (int c = tid; c < 768; c += 256) {
        const float* wr = &wproj[(size_t)c*768 + hoff];
        float s = 0.f;
        for (int d = 0; d < 64; d++) s += od[d] * q8f(wr[d]);
        atomicAdd(&out[(mrow + q0 + row)*768 + c], s);
      }
    }
    __syncthreads();
  }
}

extern "C" void kernel_launch(void* const* d_in, const int* in_sizes, int n_in,
                              void* d_out, int out_size, void* d_ws, size_t ws_size,
                              hipStream_t stream) {
  const float* x      = (const float*)d_in[0];
  const float* w_qkv  = (const float*)d_in[1];
  const float* w_proj = (const float*)d_in[2];
  const float* b_proj = (const float*)d_in[3];
  float* out = (float*)d_out;

  _Float16* p = (_Float16*)d_ws;
  _Float16* xt  = p;  p += (size_t)NM*768;        // tiled [64][12][8192]
  _Float16* wqt = p;  p += (size_t)1536*768;      // tiled [12][12][8192]
  _Float16* Qm  = p;  p += (size_t)NM*768;        // [m][768]
  _Float16* KmT = p;  p += (size_t)NM*768;        // [bh][16][4096] swizzled

  dim3 blk(256);
  k_pre <<<dim3(9792), blk, 0, stream>>>(x, w_qkv, b_proj, xt, wqt, out);
  k_qk  <<<dim3(64, 12), blk, 0, stream>>>(xt, wqt, Qm, KmT);
  k_attn<<<dim3(96, 8), blk, 0, stream>>>(Qm, KmT, x, w_qkv, w_proj, out);
}

// Round 2
// 131.793 us; speedup vs baseline: 1.0229x; 1.0031x over previous
//
#include <hip/hip_runtime.h>

// Problem constants
#define NB 8
#define NSEQ 1024
#define NC 768
#define NH 12
#define ND 64
#define NM 8192                     // NB*NSEQ rows

typedef _Float16 v8h __attribute__((ext_vector_type(8)));
typedef float v4f __attribute__((ext_vector_type(4)));

__device__ __forceinline__ float q8f(float x){ return rintf(x*128.f)*0.0078125f; }
__device__ __forceinline__ float q4f(float x){ return rintf(x*8.f)*0.125f; }

// swizzled half-index: row r, 8-half granule g (row stride 64 halves)
__device__ __forceinline__ int swz(int r, int g){ return (r<<6) + (((g ^ (r & 7)) & 7)<<3); }

// async 16B global->LDS (lds dest = uniform base + lane*16)
__device__ __forceinline__ void async_cp16(const _Float16* g, _Float16* l) {
  __builtin_amdgcn_global_load_lds(
      (const __attribute__((address_space(1))) unsigned int*)g,
      (__attribute__((address_space(3))) unsigned int*)l, 16, 0, 0);
}

// ---------------------------------------------------------------------------
// Kernel 0: (a) fp32 -> q8 fp16 tiled/swizzled for x and w_qk (first 1536
// rows of w_qkv); (b) fill out with bias (hit fix-ups atomicAdd later).
// ---------------------------------------------------------------------------
__global__ __launch_bounds__(256) void k_pre(const float* __restrict__ x,
                                             const float* __restrict__ wq,
                                             const float* __restrict__ bias,
                                             _Float16* __restrict__ xt,
                                             _Float16* __restrict__ wqt,
                                             float* __restrict__ out) {
  int b = blockIdx.x;
  if (b < 3648) {
    const float* src; _Float16* dst; int gid;
    if (b < 3072) { src = x;  dst = xt;  gid = b*256 + threadIdx.x; }
    else          { src = wq; dst = wqt; gid = (b-3072)*256 + threadIdx.x; }
    int tile = gid / 12288;               // 12 chunks * 1024 granules
    int rem  = gid - tile*12288;
    int chunk = rem >> 10, idx = rem & 1023;
    int r = idx >> 3, g = idx & 7;
    const float* s = src + (size_t)(tile*128 + r)*768 + chunk*64 + g*8;
    float4 v0 = *(const float4*)s, v1 = *(const float4*)(s + 4);
    v8h o;
    o[0]=(_Float16)q8f(v0.x); o[1]=(_Float16)q8f(v0.y); o[2]=(_Float16)q8f(v0.z); o[3]=(_Float16)q8f(v0.w);
    o[4]=(_Float16)q8f(v1.x); o[5]=(_Float16)q8f(v1.y); o[6]=(_Float16)q8f(v1.z); o[7]=(_Float16)q8f(v1.w);
    *(v8h*)&dst[((size_t)tile*12 + chunk)*8192 + swz(r, g)] = o;
  } else {
    int gid = (b - 3648)*256 + threadIdx.x;   // over 1572864 float4s
    int c4 = gid % 192;
    ((float4*)out)[gid] = ((const float4*)bias)[c4];
  }
}

// MFMA on one staged 128x128(A) x 128x64-chunk: 16x16x32 f16
__device__ __forceinline__ void mfma_tile(const _Float16* Ah, const _Float16* Bh,
                                          int WR0, int l15, int quad, v4f acc[2][8]) {
#pragma unroll
  for (int ks = 0; ks < 2; ks++) {
    v8h a0 = *(const v8h*)&Ah[swz(WR0 + l15,      ks*4 + quad)];
    v8h a1 = *(const v8h*)&Ah[swz(WR0 + 16 + l15, ks*4 + quad)];
#pragma unroll
    for (int nt = 0; nt < 8; nt++) {
      v8h b = *(const v8h*)&Bh[swz(nt*16 + l15, ks*4 + quad)];
      acc[0][nt] = __builtin_amdgcn_mfma_f32_16x16x32_f16(a0, b, acc[0][nt], 0, 0, 0);
      acc[1][nt] = __builtin_amdgcn_mfma_f32_16x16x32_f16(a1, b, acc[1][nt], 0, 0, 0);
    }
  }
}

// ---------------------------------------------------------------------------
// Kernel 1: Q/K GEMM (M=8192, N=1536, K=768). 128x128 tile, 64KB LDS,
// 2 blocks/CU. T4 counted-vmcnt pipeline: per K-step issue next stage's 8
// global_load_lds, wait vmcnt(8) (own previous stage landed; new stage stays
// in flight across the barrier), raw s_barrier, MFMA, raw s_barrier (all
// waves done reading buf before next-iteration stage can overwrite it).
// No vmcnt(0) drain in the main loop.
// ---------------------------------------------------------------------------
__global__ __launch_bounds__(256) void k_qk(const _Float16* __restrict__ xt,
                                            const _Float16* __restrict__ wqt,
                                            _Float16* __restrict__ Qm,
                                            _Float16* __restrict__ KmT) {
  __shared__ _Float16 S[2][16384];        // per buf: A 8192 | B 8192
  const int tid  = threadIdx.x;
  const int lane = tid & 63;
  const int quad = lane >> 4;
  const int l15  = lane & 15;
  const int wid  = tid >> 6;
  const int WR0  = wid * 32;
  const int m0 = blockIdx.x * 128, n0 = blockIdx.y * 128;
  const _Float16* Asrc = xt  + (size_t)blockIdx.x * 12 * 8192;
  const _Float16* Bsrc = wqt + (size_t)blockIdx.y * 12 * 8192;

  auto stage = [&](int kc, int bi) {
    const _Float16* a = Asrc + kc*8192;
    const _Float16* bsc = Bsrc + kc*8192;
#pragma unroll
    for (int s = 0; s < 8; s++) {
      int seg = wid*8 + s;
      const _Float16* g = (seg < 16 ? a + seg*512 : bsc + (seg-16)*512) + lane*8;
      async_cp16(g, &S[bi][seg*512]);
    }
  };

  v4f acc[2][8] = {};
  stage(0, 0);
#pragma unroll 1
  for (int kc = 0; kc < 12; kc++) {
    if (kc + 1 < 12) {
      stage(kc + 1, (kc + 1) & 1);
      asm volatile("s_waitcnt vmcnt(8)" ::: "memory");   // stage(kc) landed
    } else {
      asm volatile("s_waitcnt vmcnt(0)" ::: "memory");
    }
    __builtin_amdgcn_s_barrier();                        // all waves' stage(kc) visible
    mfma_tile(&S[kc & 1][0], &S[kc & 1][8192], WR0, l15, quad, acc);
    __builtin_amdgcn_s_barrier();                        // buf kc&1 free for reuse
  }

  const int which = (n0 >= 768);          // 0: Q block, 1: K block
  _Float16* P = &S[0][0];                 // bounce area 128x132
  __syncthreads();
#pragma unroll
  for (int mt = 0; mt < 2; mt++)
#pragma unroll
    for (int nt = 0; nt < 8; nt++)
#pragma unroll
      for (int rr = 0; rr < 4; rr++) {
        float v = q8f(acc[mt][nt][rr]);
        float qm = (which == 0) ? q4f(v) * 0.125f : q4f(v);
        P[(WR0 + mt*16 + quad*4 + rr)*132 + nt*16 + l15] = (_Float16)qm;
      }
  __syncthreads();
  int c0 = n0 - which*768;
#pragma unroll
  for (int t = 0; t < 8; t++) {
    int idx = tid + t*256;
    int r = idx >> 4, cg = idx & 15;
    v8h val = *(const v8h*)&P[r*132 + cg*8];
    if (which == 0) {
      *(v8h*)&Qm[(size_t)(m0 + r)*768 + c0 + cg*8] = val;
    } else {
      int m = m0 + r, col = c0 + cg*8;
      int bI = m >> 10, n = m & 1023;
      int h = col >> 6, g = (col >> 3) & 7;
      size_t dst = ((size_t)(bI*NH + h)*16 + (n >> 6))*4096 + swz(n & 63, g);
      *(v8h*)&KmT[dst] = val;
    }
  }
}

// ---------------------------------------------------------------------------
// Kernel 2: MSB screen + slow path + inline hit fix-up. 128-row Q tiles.
// TWO K-chunks staged per barrier; same T4 counted-vmcnt pipeline as k_qk
// (vmcnt(4): 4 global_load_lds per thread per stage). Grid (96, 8): bh
// fastest so q-tiles sharing a KmT panel share an XCD.
// Screen: per-chunk group max; running (max, 2nd-group-max). Underestimating
// m2 only ADDS slow-path candidates (never false negatives). gap<=4.5 proves
// pm <= 0.989 < 0.99.
// ---------------------------------------------------------------------------
__global__ __launch_bounds__(256) void k_attn(const _Float16* __restrict__ QmG,
                                              const _Float16* __restrict__ KmT,
                                              const float* __restrict__ x,
                                              const float* __restrict__ wqkv,
                                              const float* __restrict__ wproj,
                                              float* __restrict__ out) {
  __shared__ _Float16 S2[2][8192];        // two chunks per buffer
  __shared__ float rowm[128];
  __shared__ int   cand[128];
  __shared__ int   hrowA[128];
  __shared__ int   hcolA[128];
  __shared__ float qf[64], kf[64], vf[64];
  __shared__ float od[64];
  __shared__ float pps;
  __shared__ int   cnt, hcnt;

  const int tid  = threadIdx.x;
  const int lane = tid & 63;
  const int quad = lane >> 4;
  const int l15  = lane & 15;
  const int wid  = tid >> 6;
  const int R0   = wid * 16;
  const int bh = blockIdx.x;              // bh fastest -> same-XCD K reuse
  const int q0 = blockIdx.y * 128;
  const int bb = bh / NH, hb = bh % NH;
  const size_t mrow = (size_t)bb * NSEQ;
  const int hoff = hb * 64;
  const _Float16* KmB = KmT + (size_t)bh * 16 * 4096;

  if (tid == 0) { cnt = 0; hcnt = 0; }

  auto stageK2 = [&](int kp, int bi) {     // stages chunks 2kp, 2kp+1
#pragma unroll
    for (int s = 0; s < 4; s++) {
      int seg = wid*4 + s;                 // 16 segs x 512 halves
      async_cp16(KmB + kp*8192 + seg*512 + lane*8, &S2[bi][seg*512]);
    }
  };

  // A-fragments for both 64-row bands
  v8h aM[2][2];
#pragma unroll
  for (int b2 = 0; b2 < 2; b2++)
#pragma unroll
    for (int ks = 0; ks < 2; ks++)
      aM[b2][ks] = *(const v8h*)&QmG[(mrow + q0 + b2*64 + R0 + l15)*768 + hoff + ks*32 + quad*8];

  float lm[2][4], lm2[2][4];
#pragma unroll
  for (int b2 = 0; b2 < 2; b2++)
#pragma unroll
    for (int r = 0; r < 4; r++) { lm[b2][r] = -1e30f; lm2[b2][r] = -1e30f; }

  stageK2(0, 0);
#pragma unroll 1
  for (int kp = 0; kp < 8; kp++) {
    if (kp + 1 < 8) {
      stageK2(kp + 1, (kp + 1) & 1);
      asm volatile("s_waitcnt vmcnt(4)" ::: "memory");   // stage(kp) landed
    } else {
      asm volatile("s_waitcnt vmcnt(0)" ::: "memory");
    }
    __builtin_amdgcn_s_barrier();                        // all waves' stage(kp) visible
#pragma unroll
    for (int half = 0; half < 2; half++) {
      const _Float16* Kms = &S2[kp & 1][half*4096];
      v4f a0[4] = {}, a1[4] = {};
      __builtin_amdgcn_s_setprio(1);       // T5: favor MFMA-issuing wave
#pragma unroll
      for (int nt = 0; nt < 4; nt++)
#pragma unroll
        for (int ks = 0; ks < 2; ks++) {
          v8h b = *(const v8h*)&Kms[swz(l15 + 16*nt, ks*4 + quad)];
          a0[nt] = __builtin_amdgcn_mfma_f32_16x16x32_f16(aM[0][ks], b, a0[nt], 0, 0, 0);
          a1[nt] = __builtin_amdgcn_mfma_f32_16x16x32_f16(aM[1][ks], b, a1[nt], 0, 0, 0);
        }
      __builtin_amdgcn_s_setprio(0);
#pragma unroll
      for (int r = 0; r < 4; r++) {
        float c0 = fmaxf(fmaxf(a0[0][r], a0[1][r]), fmaxf(a0[2][r], a0[3][r]));
        lm2[0][r] = fmaxf(lm2[0][r], fminf(lm[0][r], c0));
        lm[0][r]  = fmaxf(lm[0][r], c0);
        float c1 = fmaxf(fmaxf(a1[0][r], a1[1][r]), fmaxf(a1[2][r], a1[3][r]));
        lm2[1][r] = fmaxf(lm2[1][r], fminf(lm[1][r], c1));
        lm[1][r]  = fmaxf(lm[1][r], c1);
      }
    }
    __builtin_amdgcn_s_barrier();                        // buf kp&1 free for reuse
  }
  // butterfly top-2 merge across the 16 lanes of each quad-row
#pragma unroll
  for (int b2 = 0; b2 < 2; b2++)
#pragma unroll
    for (int r = 0; r < 4; r++) {
      float m = lm[b2][r], m2 = lm2[b2][r];
#pragma unroll
      for (int o = 1; o < 16; o <<= 1) {
        float om  = __shfl_xor(m, o);
        float om2 = __shfl_xor(m2, o);
        m2 = fmaxf(fmaxf(m2, om2), fminf(m, om));
        m  = fmaxf(m, om);
      }
      if (l15 == 0 && (m - m2) > 4.5f) {
        int row = b2*64 + R0 + quad*4 + r;
        rowm[row] = m;
        int ix = atomicAdd(&cnt, 1);
        cand[ix] = row;
      }
    }
  __syncthreads();

  // slow path: exact denominator + argmax for candidates (one wave each)
  int nc = cnt;
  for (int ci = wid; ci < nc; ci += 4) {
    int row = cand[ci];
    float m = rowm[row];
    const _Float16* qrow = &QmG[(mrow + q0 + row)*768 + hoff];
    float l = 0.f, bmax = -1e30f;
    int bcol = 0;
    for (int t = 0; t < 16; t++) {
      float s = 0.f;
#pragma unroll
      for (int g = 0; g < 8; g++) {
        v8h qa = *(const v8h*)&qrow[g*8];
        v8h kb = *(const v8h*)&KmB[t*4096 + swz(lane, g)];
#pragma unroll
        for (int j = 0; j < 8; j++) s += (float)qa[j] * (float)kb[j];
      }
      l += expf(s - m);
      if (s > bmax) { bmax = s; bcol = t*64 + lane; }
    }
#pragma unroll
    for (int o = 1; o < 64; o <<= 1) {
      l += __shfl_xor(l, o);
      float ov = __shfl_xor(bmax, o);
      int   oc = __shfl_xor(bcol, o);
      if (ov > bmax || (ov == bmax && oc < bcol)) { bmax = ov; bcol = oc; }
    }
    if (lane == 0 && (1.0f / l) > 0.99f) {
      int ix = atomicAdd(&hcnt, 1);
      hrowA[ix] = row; hcolA[ix] = bcol;
    }
  }
  __syncthreads();

  // hit fix-up (rare; usually hcnt == 0)
  int nh = hcnt;
  for (int hi = 0; hi < nh; hi++) {
    int row = hrowA[hi], cst = hcolA[hi];
    if (tid < 192) {                     // recompute q/k/v head-slices exactly
      int d = tid & 63, part = tid >> 6; // 0:q 1:k 2:v
      int wrow = part*768 + hoff + d;
      int xrow = (part == 0) ? (int)(mrow + q0 + row) : (int)(mrow + cst);
      const float* xr = &x[(size_t)xrow*768];
      const float* wr = &wqkv[(size_t)wrow*768];
      float s = 0.f;
      for (int k = 0; k < 768; k++) s += q8f(xr[k]) * q8f(wr[k]);
      float v = q8f(s);
      if (part == 0) qf[d] = v; else if (part == 1) kf[d] = v; else vf[d] = v;
    }
    __syncthreads();
    if (tid == 0) {
      float s = 0.f;
      for (int d = 0; d < 64; d++) s += qf[d]*kf[d];
      float sf = s * 0.125f;
      float m2 = fmaxf(sf, 0.f);
      float l2 = expf(sf - m2) + 1023.f*expf(-m2);
      pps = rintf(expf(sf - m2)/l2*128.f)*0.0078125f;
    }
    __syncthreads();
    float p = pps;                        // block-uniform
    if (p != 0.f) {
      if (tid < 64) od[tid] = q8f(p * vf[tid]);
      __syncthreads();
      for (int c = tid; c < 768; c += 256) {
        const float* wr = &wproj[(size_t)c*768 + hoff];
        float s = 0.f;
        for (int d = 0; d < 64; d++) s += od[d] * q8f(wr[d]);
        atomicAdd(&out[(mrow + q0 + row)*768 + c], s);
      }
    }
    __syncthreads();
  }
}

extern "C" void kernel_launch(void* const* d_in, const int* in_sizes, int n_in,
                              void* d_out, int out_size, void* d_ws, size_t ws_size,
                              hipStream_t stream) {
  const float* x      = (const float*)d_in[0];
  const float* w_qkv  = (const float*)d_in[1];
  const float* w_proj = (const float*)d_in[2];
  const float* b_proj = (const float*)d_in[3];
  float* out = (float*)d_out;

  _Float16* p = (_Float16*)d_ws;
  _Float16* xt  = p;  p += (size_t)NM*768;        // tiled [64][12][8192]
  _Float16* wqt = p;  p += (size_t)1536*768;      // tiled [12][12][8192]
  _Float16* Qm  = p;  p += (size_t)NM*768;        // [m][768]
  _Float16* KmT = p;  p += (size_t)NM*768;        // [bh][16][4096] swizzled

  dim3 blk(256);
  k_pre <<<dim3(9792), blk, 0, stream>>>(x, w_qkv, b_proj, xt, wqt, out);
  k_qk  <<<dim3(64, 12), blk, 0, stream>>>(xt, wqt, Qm, KmT);
  k_attn<<<dim3(96, 8), blk, 0, stream>>>(Qm, KmT, x, w_qkv, w_proj, out);
}

// Round 3
// 122.795 us; speedup vs baseline: 1.0979x; 1.0733x over previous
//
#include <hip/hip_runtime.h>

// Problem constants
#define NB 8
#define NSEQ 1024
#define NC 768
#define NH 12
#define ND 64
#define NM 8192                     // NB*NSEQ rows

typedef _Float16 v8h __attribute__((ext_vector_type(8)));
typedef float v4f __attribute__((ext_vector_type(4)));
typedef int   v4i __attribute__((ext_vector_type(4)));

__device__ __forceinline__ float q8f(float x){ return rintf(x*128.f)*0.0078125f; }
__device__ __forceinline__ int imax2(int a, int b){ return a > b ? a : b; }
__device__ __forceinline__ int imin2(int a, int b){ return a < b ? a : b; }

// swizzled half-index: row r, 8-half granule g (row stride 64 halves)
__device__ __forceinline__ int swz(int r, int g){ return (r<<6) + (((g ^ (r & 7)) & 7)<<3); }

// async 16B global->LDS (lds dest = uniform base + lane*16)
__device__ __forceinline__ void async_cp16(const void* g, void* l) {
  __builtin_amdgcn_global_load_lds(
      (const __attribute__((address_space(1))) unsigned int*)g,
      (__attribute__((address_space(3))) unsigned int*)l, 16, 0, 0);
}

// ---------------------------------------------------------------------------
// Kernel 0: (a) fp32 -> q8 fp16 tiled/swizzled for x and w_qk (first 1536
// rows of w_qkv); (b) fill out with bias (hit fix-ups atomicAdd later).
// ---------------------------------------------------------------------------
__global__ __launch_bounds__(256) void k_pre(const float* __restrict__ x,
                                             const float* __restrict__ wq,
                                             const float* __restrict__ bias,
                                             _Float16* __restrict__ xt,
                                             _Float16* __restrict__ wqt,
                                             float* __restrict__ out) {
  int b = blockIdx.x;
  if (b < 3648) {
    const float* src; _Float16* dst; int gid;
    if (b < 3072) { src = x;  dst = xt;  gid = b*256 + threadIdx.x; }
    else          { src = wq; dst = wqt; gid = (b-3072)*256 + threadIdx.x; }
    int tile = gid / 12288;               // 12 chunks * 1024 granules
    int rem  = gid - tile*12288;
    int chunk = rem >> 10, idx = rem & 1023;
    int r = idx >> 3, g = idx & 7;
    const float* s = src + (size_t)(tile*128 + r)*768 + chunk*64 + g*8;
    float4 v0 = *(const float4*)s, v1 = *(const float4*)(s + 4);
    v8h o;
    o[0]=(_Float16)q8f(v0.x); o[1]=(_Float16)q8f(v0.y); o[2]=(_Float16)q8f(v0.z); o[3]=(_Float16)q8f(v0.w);
    o[4]=(_Float16)q8f(v1.x); o[5]=(_Float16)q8f(v1.y); o[6]=(_Float16)q8f(v1.z); o[7]=(_Float16)q8f(v1.w);
    *(v8h*)&dst[((size_t)tile*12 + chunk)*8192 + swz(r, g)] = o;
  } else {
    int gid = (b - 3648)*256 + threadIdx.x;   // over 1572864 float4s
    int c4 = gid % 192;
    ((float4*)out)[gid] = ((const float4*)bias)[c4];
  }
}

// MFMA on one staged 128x128(A) x 128x64-chunk: 16x16x32 f16
__device__ __forceinline__ void mfma_tile(const _Float16* Ah, const _Float16* Bh,
                                          int WR0, int l15, int quad, v4f acc[2][8]) {
#pragma unroll
  for (int ks = 0; ks < 2; ks++) {
    v8h a0 = *(const v8h*)&Ah[swz(WR0 + l15,      ks*4 + quad)];
    v8h a1 = *(const v8h*)&Ah[swz(WR0 + 16 + l15, ks*4 + quad)];
#pragma unroll
    for (int nt = 0; nt < 8; nt++) {
      v8h b = *(const v8h*)&Bh[swz(nt*16 + l15, ks*4 + quad)];
      acc[0][nt] = __builtin_amdgcn_mfma_f32_16x16x32_f16(a0, b, acc[0][nt], 0, 0, 0);
      acc[1][nt] = __builtin_amdgcn_mfma_f32_16x16x32_f16(a1, b, acc[1][nt], 0, 0, 0);
    }
  }
}

// ---------------------------------------------------------------------------
// Kernel 1: Q/K GEMM (M=8192, N=1536, K=768). 128x128 tile, 64KB LDS.
// T4 counted-vmcnt pipeline (null but harmless; kept from R1).
// NEW: epilogue emits i8 MSB integers I = rint(q8(acc)*8)  (q_msb = I/8;
// score reconstruction downstream is I_q*I_k/512, exact).
//   Q-blocks -> QmI [m][768] i8 ; K-blocks -> KmI [bh][1024][64] i8.
// ---------------------------------------------------------------------------
__global__ __launch_bounds__(256) void k_qk(const _Float16* __restrict__ xt,
                                            const _Float16* __restrict__ wqt,
                                            char* __restrict__ QmI,
                                            char* __restrict__ KmI) {
  __shared__ _Float16 S[2][16384];        // per buf: A 8192 | B 8192
  const int tid  = threadIdx.x;
  const int lane = tid & 63;
  const int quad = lane >> 4;
  const int l15  = lane & 15;
  const int wid  = tid >> 6;
  const int WR0  = wid * 32;
  const int m0 = blockIdx.x * 128, n0 = blockIdx.y * 128;
  const _Float16* Asrc = xt  + (size_t)blockIdx.x * 12 * 8192;
  const _Float16* Bsrc = wqt + (size_t)blockIdx.y * 12 * 8192;

  auto stage = [&](int kc, int bi) {
    const _Float16* a = Asrc + kc*8192;
    const _Float16* bsc = Bsrc + kc*8192;
#pragma unroll
    for (int s = 0; s < 8; s++) {
      int seg = wid*8 + s;
      const _Float16* g = (seg < 16 ? a + seg*512 : bsc + (seg-16)*512) + lane*8;
      async_cp16(g, &S[bi][seg*512]);
    }
  };

  v4f acc[2][8] = {};
  stage(0, 0);
#pragma unroll 1
  for (int kc = 0; kc < 12; kc++) {
    if (kc + 1 < 12) {
      stage(kc + 1, (kc + 1) & 1);
      asm volatile("s_waitcnt vmcnt(8)" ::: "memory");   // stage(kc) landed
    } else {
      asm volatile("s_waitcnt vmcnt(0)" ::: "memory");
    }
    __builtin_amdgcn_s_barrier();                        // all waves' stage(kc) visible
    mfma_tile(&S[kc & 1][0], &S[kc & 1][8192], WR0, l15, quad, acc);
    __builtin_amdgcn_s_barrier();                        // buf kc&1 free for reuse
  }

  const int which = (n0 >= 768);          // 0: Q block, 1: K block
  char* P8 = (char*)&S[0][0];             // bounce area 128 x (stride 144) i8
  __syncthreads();
#pragma unroll
  for (int mt = 0; mt < 2; mt++)
#pragma unroll
    for (int nt = 0; nt < 8; nt++)
#pragma unroll
      for (int rr = 0; rr < 4; rr++) {
        float v = q8f(acc[mt][nt][rr]);
        int qi = (int)rintf(v * 8.f);     // MSB integer, |qi| small (fits i8)
        P8[(WR0 + mt*16 + quad*4 + rr)*144 + nt*16 + l15] = (char)qi;
      }
  __syncthreads();
  int c0 = n0 - which*768;
#pragma unroll
  for (int t = 0; t < 4; t++) {
    int idx = tid + t*256;                // 1024 granules of 16B
    int r = idx >> 3, cg = idx & 7;
    v4i val = *(const v4i*)&P8[r*144 + cg*16];
    if (which == 0) {
      *(v4i*)&QmI[(size_t)(m0 + r)*768 + c0 + cg*16] = val;
    } else {
      int m = m0 + r, n = m & 1023, bI = m >> 10;
      int h = (c0 + cg*16) >> 6, d0 = (cg & 3)*16;
      *(v4i*)&KmI[(((size_t)(bI*NH + h)*1024 + n) << 6) + d0] = val;
    }
  }
}

// ---------------------------------------------------------------------------
// Kernel 2: MSB screen + slow path + inline hit fix-up. 128-row Q tiles.
// i8 screen: mfma_i32_16x16x64_i8, K=64 = whole head dim per MFMA.
// Integer scores I (= score*512, exact). Gap test (m-m2)>4.5  <=>  I-gap>2304
// (both sides multiples of 1/512; exact equivalence, no false negatives).
// 4 kp iterations x 256 KV rows (16 KB staged/kp), counted-vmcnt pipeline.
// Grid (96, 8): bh fastest so q-tiles sharing a K panel share an XCD.
// ---------------------------------------------------------------------------
__global__ __launch_bounds__(256) void k_attn(const char* __restrict__ QmI,
                                              const char* __restrict__ KmI,
                                              const float* __restrict__ x,
                                              const float* __restrict__ wqkv,
                                              const float* __restrict__ wproj,
                                              float* __restrict__ out) {
  __shared__ char  S2[2][16384];          // 256 KV rows x 64 i8 per buffer
  __shared__ float rowm[128];
  __shared__ int   cand[128];
  __shared__ int   hrowA[128];
  __shared__ int   hcolA[128];
  __shared__ float qf[64], kf[64], vf[64];
  __shared__ float od[64];
  __shared__ float pps;
  __shared__ int   cnt, hcnt;

  const int tid  = threadIdx.x;
  const int lane = tid & 63;
  const int quad = lane >> 4;
  const int l15  = lane & 15;
  const int wid  = tid >> 6;
  const int R0   = wid * 16;
  const int bh = blockIdx.x;              // bh fastest -> same-XCD K reuse
  const int q0 = blockIdx.y * 128;
  const int bb = bh / NH, hb = bh % NH;
  const size_t mrow = (size_t)bb * NSEQ;
  const int hoff = hb * 64;
  const char* KmB = KmI + (size_t)bh * 1024 * 64;

  if (tid == 0) { cnt = 0; hcnt = 0; }

  auto stageK = [&](int kp, int bi) {      // stages rows [kp*256, kp*256+256)
#pragma unroll
    for (int s = 0; s < 4; s++) {
      int seg = wid*4 + s;                 // 16 segs x 1024 B
      async_cp16(KmB + kp*16384 + seg*1024 + lane*16, &S2[bi][seg*1024]);
    }
  };

  // Q fragments (i8, K=64: one 16B fragment per 64-row band)
  v4i aQ[2];
#pragma unroll
  for (int b2 = 0; b2 < 2; b2++)
    aQ[b2] = *(const v4i*)&QmI[(mrow + q0 + b2*64 + R0 + l15)*768 + hoff + quad*16];

  int lm[2][4], lm2[2][4];
#pragma unroll
  for (int b2 = 0; b2 < 2; b2++)
#pragma unroll
    for (int r = 0; r < 4; r++) { lm[b2][r] = -1073741824; lm2[b2][r] = -1073741824; }

  stageK(0, 0);
#pragma unroll 1
  for (int kp = 0; kp < 4; kp++) {
    if (kp + 1 < 4) {
      stageK(kp + 1, (kp + 1) & 1);
      asm volatile("s_waitcnt vmcnt(4)" ::: "memory");   // stage(kp) landed
    } else {
      asm volatile("s_waitcnt vmcnt(0)" ::: "memory");
    }
    __builtin_amdgcn_s_barrier();                        // staged tile visible
#pragma unroll
    for (int g64 = 0; g64 < 4; g64++) {                  // 64-row score groups
      const char* Ks = &S2[kp & 1][g64*4096];
      v4i c0a[4] = {}, c1a[4] = {};
      __builtin_amdgcn_s_setprio(1);
#pragma unroll
      for (int nt = 0; nt < 4; nt++) {
        v4i b = *(const v4i*)&Ks[(nt*16 + l15)*64 + quad*16];
        c0a[nt] = __builtin_amdgcn_mfma_i32_16x16x64_i8(aQ[0], b, c0a[nt], 0, 0, 0);
        c1a[nt] = __builtin_amdgcn_mfma_i32_16x16x64_i8(aQ[1], b, c1a[nt], 0, 0, 0);
      }
      __builtin_amdgcn_s_setprio(0);
#pragma unroll
      for (int r = 0; r < 4; r++) {
        int g0 = imax2(imax2(c0a[0][r], c0a[1][r]), imax2(c0a[2][r], c0a[3][r]));
        lm2[0][r] = imax2(lm2[0][r], imin2(lm[0][r], g0));
        lm[0][r]  = imax2(lm[0][r], g0);
        int g1 = imax2(imax2(c1a[0][r], c1a[1][r]), imax2(c1a[2][r], c1a[3][r]));
        lm2[1][r] = imax2(lm2[1][r], imin2(lm[1][r], g1));
        lm[1][r]  = imax2(lm[1][r], g1);
      }
    }
    __builtin_amdgcn_s_barrier();                        // buf kp&1 free
  }
  // butterfly top-2 merge across the 16 lanes of each quad-row (integer)
#pragma unroll
  for (int b2 = 0; b2 < 2; b2++)
#pragma unroll
    for (int r = 0; r < 4; r++) {
      int m = lm[b2][r], m2 = lm2[b2][r];
#pragma unroll
      for (int o = 1; o < 16; o <<= 1) {
        int om  = __shfl_xor(m, o);
        int om2 = __shfl_xor(m2, o);
        m2 = imax2(imax2(m2, om2), imin2(m, om));
        m  = imax2(m, om);
      }
      if (l15 == 0 && (m - m2) > 2304) {                 // 4.5 * 512, exact
        int row = b2*64 + R0 + quad*4 + r;
        rowm[row] = (float)m * 0.001953125f;             // /512, exact
        int ix = atomicAdd(&cnt, 1);
        cand[ix] = row;
      }
    }
  __syncthreads();

  // slow path: exact denominator + argmax for candidates (one wave each)
  int nc = cnt;
  for (int ci = wid; ci < nc; ci += 4) {
    int row = cand[ci];
    float m = rowm[row];
    const char* qrow = &QmI[(mrow + q0 + row)*768 + hoff];
    float l = 0.f, bmax = -1e30f;
    int bcol = 0;
    for (int t = 0; t < 16; t++) {
      const char* kb = &KmB[(size_t)(t*64 + lane)*64];
      int si = 0;
#pragma unroll
      for (int j = 0; j < 64; j++) si += (int)qrow[j] * (int)kb[j];
      float s = (float)si * 0.001953125f;                // I/512, exact
      l += expf(s - m);
      if (s > bmax) { bmax = s; bcol = t*64 + lane; }
    }
#pragma unroll
    for (int o = 1; o < 64; o <<= 1) {
      l += __shfl_xor(l, o);
      float ov = __shfl_xor(bmax, o);
      int   oc = __shfl_xor(bcol, o);
      if (ov > bmax || (ov == bmax && oc < bcol)) { bmax = ov; bcol = oc; }
    }
    if (lane == 0 && (1.0f / l) > 0.99f) {
      int ix = atomicAdd(&hcnt, 1);
      hrowA[ix] = row; hcolA[ix] = bcol;
    }
  }
  __syncthreads();

  // hit fix-up (rare; usually hcnt == 0)
  int nh = hcnt;
  for (int hi = 0; hi < nh; hi++) {
    int row = hrowA[hi], cst = hcolA[hi];
    if (tid < 192) {                     // recompute q/k/v head-slices exactly
      int d = tid & 63, part = tid >> 6; // 0:q 1:k 2:v
      int wrow = part*768 + hoff + d;
      int xrow = (part == 0) ? (int)(mrow + q0 + row) : (int)(mrow + cst);
      const float* xr = &x[(size_t)xrow*768];
      const float* wr = &wqkv[(size_t)wrow*768];
      float s = 0.f;
      for (int k = 0; k < 768; k++) s += q8f(xr[k]) * q8f(wr[k]);
      float v = q8f(s);
      if (part == 0) qf[d] = v; else if (part == 1) kf[d] = v; else vf[d] = v;
    }
    __syncthreads();
    if (tid == 0) {
      float s = 0.f;
      for (int d = 0; d < 64; d++) s += qf[d]*kf[d];
      float sf = s * 0.125f;
      float m2 = fmaxf(sf, 0.f);
      float l2 = expf(sf - m2) + 1023.f*expf(-m2);
      pps = rintf(expf(sf - m2)/l2*128.f)*0.0078125f;
    }
    __syncthreads();
    float p = pps;                        // block-uniform
    if (p != 0.f) {
      if (tid < 64) od[tid] = q8f(p * vf[tid]);
      __syncthreads();
      for (int c = tid; c < 768; c += 256) {
        const float* wr = &wproj[(size_t)c*768 + hoff];
        float s = 0.f;
        for (int d = 0; d < 64; d++) s += od[d] * q8f(wr[d]);
        atomicAdd(&out[(mrow + q0 + row)*768 + c], s);
      }
    }
    __syncthreads();
  }
}

extern "C" void kernel_launch(void* const* d_in, const int* in_sizes, int n_in,
                              void* d_out, int out_size, void* d_ws, size_t ws_size,
                              hipStream_t stream) {
  const float* x      = (const float*)d_in[0];
  const float* w_qkv  = (const float*)d_in[1];
  const float* w_proj = (const float*)d_in[2];
  const float* b_proj = (const float*)d_in[3];
  float* out = (float*)d_out;

  char* p = (char*)d_ws;
  _Float16* xt  = (_Float16*)p;  p += (size_t)NM*768*2;     // tiled [64][12][8192] f16
  _Float16* wqt = (_Float16*)p;  p += (size_t)1536*768*2;   // tiled [12][12][8192] f16
  char* QmI = p;  p += (size_t)NM*768;                      // [m][768] i8
  char* KmI = p;  p += (size_t)NM*768;                      // [bh][1024][64] i8

  dim3 blk(256);
  k_pre <<<dim3(9792), blk, 0, stream>>>(x, w_qkv, b_proj, xt, wqt, out);
  k_qk  <<<dim3(64, 12), blk, 0, stream>>>(xt, wqt, QmI, KmI);
  k_attn<<<dim3(96, 8), blk, 0, stream>>>(QmI, KmI, x, w_qkv, w_proj, out);
}